// Round 6
// baseline (264.026 us; speedup 1.0000x reference)
//
#include <hip/hip_runtime.h>
#include <hip/hip_bf16.h>
#include <math.h>

#define HW   9216
#define WIMG 96
#define NPIX 73728  // 8 * 9216
#define CIN  256
#define CO   128

typedef __attribute__((ext_vector_type(8))) short short8v;        // 8 bf16 (4 VGPR)
typedef __attribute__((ext_vector_type(8))) unsigned short u16x8; // 8 bf16 raw
typedef __attribute__((ext_vector_type(4))) float f32x4;          // MFMA acc
typedef __attribute__((ext_vector_type(4))) unsigned u32x4;

__device__ __forceinline__ unsigned short f2bf(float f) {
    __hip_bfloat16 h = __float2bfloat16(f);
    return __builtin_bit_cast(unsigned short, h);
}
__device__ __forceinline__ float bf2f(unsigned short u) {
    unsigned v = ((unsigned)u) << 16;
    return __builtin_bit_cast(float, v);
}

// Row-XOR swizzle for [rows][64k] bf16 tiles (128B rows): reads/writes <=2-way.
__device__ __forceinline__ int swz(int row, int kb) {
    return (row * 128) + (kb ^ ((row & 7) << 4));
}

// pack two tr-read b64 results (4 bf16 each) into one 8-bf16 MFMA fragment
__device__ __forceinline__ short8v pk(unsigned long long lo, unsigned long long hi) {
    u32x4 w;
    w.x = (unsigned)lo; w.y = (unsigned)(lo >> 32);
    w.z = (unsigned)hi; w.w = (unsigned)(hi >> 32);
    return __builtin_bit_cast(short8v, w);
}

// ---------------------------------------------------------------------------
// K1 (MFMA): feat[px][128] = bf16(x[px][:]).bf16(W^T)+b   (bf16 out)
// R4 structure (grid 1728 = 576 tiles x 3 maps, 32KB LDS, XCD swizzle with
// %3 sibling adjacency) + T10 staging:
//   As: x-tile in tr-subtiled layout [pxb(8)][kq(16)][k&3(4)][px&15(16)] bf16.
//     stage = float4 global load + single ds_write_b64 (4x fewer VMEM vs R4).
//     A-frags via ds_read_b64_tr_b16 at lane-linear addrs (conflict-free);
//     delivered k-order: e<4 -> k=ks*32+lg*4+e, e>=4 -> +16.
//   Bs: W rows with k-columns PERMUTED to match that order:
//     pos(k) = (k>>5)*32 + ((k&15)>>2)*8 + ((k>>4)&1)*4 + (k&3)  (ushort4-contig)
// ---------------------------------------------------------------------------
__global__ __launch_bounds__(256) void k1_mfma(
    const float* __restrict__ x,
    const float* __restrict__ wt, const float* __restrict__ bt,
    const float* __restrict__ wp, const float* __restrict__ bp,
    const float* __restrict__ wg, const float* __restrict__ bg,
    unsigned short* __restrict__ th, unsigned short* __restrict__ ph,
    unsigned short* __restrict__ gf)
{
    __shared__ char As[16384];  // [8 pxb][16 kq][4][16] bf16
    __shared__ char Bs[16384];  // [128 n][64 k] bf16, row-XOR swz, k-permuted

    const int t   = threadIdx.x;
    const int bid = blockIdx.x;
    const int lb  = (bid & 7) * 216 + (bid >> 3);   // 1728 wg, bijective
    const int nb  = lb % 3;                         // siblings adjacent on XCD
    const int bx  = lb / 3;

    const float* W  = (nb == 0) ? wt : (nb == 1) ? wp : wg;
    const float* Bv = (nb == 0) ? bt : (nb == 1) ? bp : bg;
    unsigned short* O = (nb == 0) ? th : (nb == 1) ? ph : gf;

    const int P0 = bx * 128;               // 9216 % 128 == 0: no batch straddle
    const int b  = P0 / HW;
    const int p0 = P0 - b * HW;
    const float* xb = x + (size_t)b * CIN * HW + p0;

    const int wid = t >> 6, lane = t & 63;
    const int wm = (wid & 1) * 64, wn = (wid >> 1) * 64;
    const int l15 = lane & 15, lg = lane >> 4;

    const unsigned As0 = (unsigned)(unsigned long long)(size_t)As;
    const unsigned trb = As0 + lane * 8;   // lane-linear tr-read base

    f32x4 acc[4][4] = {};

    for (int kt = 0; kt < CIN; kt += 64) {
        if (kt) __syncthreads();
        // ---- stage A: x[kt+k][P0+px..+3] -> As subtiled (float4 + b64 write)
        #pragma unroll
        for (int it = 0; it < 8; ++it) {
            int px = (t & 15) * 4 + (it & 1) * 64;       // 0..124
            int k  = (t >> 4) + (it >> 1) * 16;          // 0..63
            float4 v4 = *(const float4*)(xb + (size_t)(kt + k) * HW + px);
            ushort4 v;
            v.x = f2bf(v4.x); v.y = f2bf(v4.y); v.z = f2bf(v4.z); v.w = f2bf(v4.w);
            int eb = ((px >> 4) * 16 + (k >> 2)) * 128 + (k & 3) * 32 + (px & 15) * 2;
            *(ushort4*)(As + eb) = v;
        }
        // ---- stage B: W[n][kt+kq*4..+3] -> Bs row n, k-permuted columns ----
        #pragma unroll
        for (int it = 0; it < 8; ++it) {
            int kq = t & 15;
            int n  = (t >> 4) + it * 16;
            float4 w4 = *(const float4*)(W + (size_t)n * CIN + kt + kq * 4);
            ushort4 v;
            v.x = f2bf(w4.x); v.y = f2bf(w4.y); v.z = f2bf(w4.z); v.w = f2bf(w4.w);
            int pos = (kq >> 3) * 32 + (kq & 3) * 8 + ((kq >> 2) & 1) * 4;
            *(ushort4*)(Bs + swz(n, pos * 2)) = v;
        }
        __syncthreads();
        #pragma unroll
        for (int ks = 0; ks < 2; ++ks) {
            short8v bq[4];
            #pragma unroll
            for (int nt = 0; nt < 4; ++nt)
                bq[nt] = *(const short8v*)(Bs + swz(wn + nt * 16 + l15, ks * 64 + lg * 16));

            // A-frags: 8 tr-reads, waitcnt INSIDE the asm => outputs valid.
            const unsigned a0 = trb + (unsigned)((wm >> 4) * 2048 + ks * 1024);
            unsigned long long L0, H0, L1, H1, L2, H2, L3, H3;
            asm volatile(
                "ds_read_b64_tr_b16 %0, %8 offset:0\n\t"
                "ds_read_b64_tr_b16 %1, %8 offset:512\n\t"
                "ds_read_b64_tr_b16 %2, %9 offset:0\n\t"
                "ds_read_b64_tr_b16 %3, %9 offset:512\n\t"
                "ds_read_b64_tr_b16 %4, %10 offset:0\n\t"
                "ds_read_b64_tr_b16 %5, %10 offset:512\n\t"
                "ds_read_b64_tr_b16 %6, %11 offset:0\n\t"
                "ds_read_b64_tr_b16 %7, %11 offset:512\n\t"
                "s_waitcnt lgkmcnt(0)"
                : "=&v"(L0), "=&v"(H0), "=&v"(L1), "=&v"(H1),
                  "=&v"(L2), "=&v"(H2), "=&v"(L3), "=&v"(H3)
                : "v"(a0), "v"(a0 + 2048u), "v"(a0 + 4096u), "v"(a0 + 6144u));
            short8v a[4];
            a[0] = pk(L0, H0); a[1] = pk(L1, H1);
            a[2] = pk(L2, H2); a[3] = pk(L3, H3);

            #pragma unroll
            for (int mt = 0; mt < 4; ++mt)
                #pragma unroll
                for (int nt = 0; nt < 4; ++nt)
                    acc[mt][nt] = __builtin_amdgcn_mfma_f32_16x16x32_bf16(
                        a[mt], bq[nt], acc[mt][nt], 0, 0, 0);
        }
    }

    // ---- epilogue: D[row=(lg*4+j)][col=l15], bias, bf16 store ----
    float bias[4];
    #pragma unroll
    for (int nt = 0; nt < 4; ++nt) bias[nt] = Bv[wn + nt * 16 + l15];
    #pragma unroll
    for (int mt = 0; mt < 4; ++mt)
        #pragma unroll
        for (int j = 0; j < 4; ++j) {
            size_t row = (size_t)(P0 + wm + mt * 16 + lg * 4 + j) * CO;
            #pragma unroll
            for (int nt = 0; nt < 4; ++nt)
                O[row + wn + nt * 16 + l15] = f2bf(acc[mt][nt][j] + bias[nt]);
        }
}

// ---------------------------------------------------------------------------
// K2: cosine-sim attention over 9 neighbors + weighted avg of g -> wa (bf16)
// (unchanged from R5)
// ---------------------------------------------------------------------------
__global__ __launch_bounds__(256) void k_attn(
    const unsigned short* __restrict__ th, const unsigned short* __restrict__ ph,
    const unsigned short* __restrict__ gf, unsigned short* __restrict__ wa)
{
    const int t   = threadIdx.x;
    const int bid = blockIdx.x;
    const int lb  = (bid & 7) * 144 + (bid >> 3);   // 1152 wg, bijective
    const int s = t >> 2, q = t & 3;
    const int P = lb * 64 + s;
    const int b = P / HW;
    const int p = P - b * HW;
    const int h = p / WIMG;
    const int w = p - h * WIMG;
    const size_t ib = (size_t)b * HW;

    size_t nbase[9];
    #pragma unroll
    for (int n = 0; n < 9; ++n) {
        int hh = h + n / 3 - 1; hh = hh < 0 ? 0 : (hh > 95 ? 95 : hh);
        int w2 = w + n % 3 - 1; w2 = w2 < 0 ? 0 : (w2 > 95 ? 95 : w2);
        nbase[n] = (ib + (size_t)hh * WIMG + w2) * CO + q * 32;
    }

    const u16x8* tv = (const u16x8*)(th + (size_t)P * CO + q * 32);
    float T32[32];
    #pragma unroll
    for (int j = 0; j < 4; ++j) {
        u16x8 v = tv[j];
        #pragma unroll
        for (int e = 0; e < 8; ++e) T32[j * 8 + e] = bf2f(v[e]);
    }
    float t4[4] = {0.f, 0.f, 0.f, 0.f};
    #pragma unroll
    for (int j = 0; j < 4; ++j)
        #pragma unroll
        for (int e = 0; e < 8; ++e)
            t4[j] = fmaf(T32[j * 8 + e], T32[j * 8 + e], t4[j]);
    float tt = (t4[0] + t4[1]) + (t4[2] + t4[3]);
    tt += __shfl_xor(tt, 1);
    tt += __shfl_xor(tt, 2);
    const float st = sqrtf(tt);

    float score[9];
    #pragma unroll
    for (int n = 0; n < 9; ++n) {
        const u16x8* pv = (const u16x8*)(ph + nbase[n]);
        float d4[4] = {0.f, 0.f, 0.f, 0.f};
        float p4[4] = {0.f, 0.f, 0.f, 0.f};
        #pragma unroll
        for (int j = 0; j < 4; ++j) {
            u16x8 v = pv[j];
            #pragma unroll
            for (int e = 0; e < 8; ++e) {
                float f = bf2f(v[e]);
                d4[j] = fmaf(T32[j * 8 + e], f, d4[j]);
                p4[j] = fmaf(f, f, p4[j]);
            }
        }
        float d  = (d4[0] + d4[1]) + (d4[2] + d4[3]);
        float pp = (p4[0] + p4[1]) + (p4[2] + p4[3]);
        d  += __shfl_xor(d, 1);  d  += __shfl_xor(d, 2);
        pp += __shfl_xor(pp, 1); pp += __shfl_xor(pp, 2);
        float den = fmaxf(sqrtf(pp) * st, 1e-8f);
        score[n] = d / den;
    }

    float mx = score[0];
    #pragma unroll
    for (int n = 1; n < 9; ++n) mx = fmaxf(mx, score[n]);
    float sum = 0.f;
    #pragma unroll
    for (int n = 0; n < 9; ++n) { score[n] = __expf(score[n] - mx); sum += score[n]; }
    const float inv = 1.f / sum;

    float acc[32];
    #pragma unroll
    for (int k = 0; k < 32; ++k) acc[k] = 0.f;

    #pragma unroll
    for (int n = 0; n < 9; ++n) {
        const u16x8* gv = (const u16x8*)(gf + nbase[n]);
        float a = score[n] * inv;
        #pragma unroll
        for (int j = 0; j < 4; ++j) {
            u16x8 v = gv[j];
            #pragma unroll
            for (int e = 0; e < 8; ++e)
                acc[j * 8 + e] = fmaf(a, bf2f(v[e]), acc[j * 8 + e]);
        }
    }

    u16x8* ov = (u16x8*)(wa + (size_t)P * CO + q * 32);
    #pragma unroll
    for (int j = 0; j < 4; ++j) {
        u16x8 o;
        #pragma unroll
        for (int e = 0; e < 8; ++e) o[e] = f2bf(acc[j * 8 + e]);
        ov[j] = o;
    }
}

// ---------------------------------------------------------------------------
// K3 (MFMA): out[b][c][p] = x + w_back . wa^T + b_back  (unchanged from R5)
// ---------------------------------------------------------------------------
__global__ __launch_bounds__(256) void k3_mfma(
    const unsigned short* __restrict__ wa, const float* __restrict__ wb,
    const float* __restrict__ bb_, const float* __restrict__ x,
    float* __restrict__ out)
{
    __shared__ char As[128 * 128];  // w_back tile [128 ch][64 k]
    __shared__ char Bs[128 * 128];  // wa tile    [128 px][64 k]

    const int t   = threadIdx.x;
    const int bid = blockIdx.x;
    const int lb  = (bid & 7) * 144 + (bid >> 3);   // 1152 wg, bijective
    const int cb  = (lb & 1) * 128;
    const int P0  = (lb >> 1) * 128;
    const int b   = P0 / HW;
    const int p0  = P0 - b * HW;

    const int wid = t >> 6, lane = t & 63;
    const int wm = (wid & 1) * 64, wn = (wid >> 1) * 64;
    const int l15 = lane & 15, lg = lane >> 4;

    f32x4 acc[4][4] = {};

    for (int kt = 0; kt < CO; kt += 64) {
        if (kt) __syncthreads();
        #pragma unroll
        for (int it = 0; it < 8; ++it) {
            int kq = t & 15;
            int n  = (t >> 4) + it * 16;
            float4 w4 = *(const float4*)(wb + (size_t)(cb + n) * CO + kt + kq * 4);
            ushort4 v;
            v.x = f2bf(w4.x); v.y = f2bf(w4.y); v.z = f2bf(w4.z); v.w = f2bf(w4.w);
            *(ushort4*)(As + swz(n, kq * 8)) = v;
        }
        #pragma unroll
        for (int it = 0; it < 4; ++it) {
            int kq = t & 7;
            int n  = (t >> 3) + it * 32;
            u16x8 u = *(const u16x8*)(wa + (size_t)(P0 + n) * CO + kt + kq * 8);
            *(u16x8*)(Bs + swz(n, kq * 16)) = u;
        }
        __syncthreads();
        #pragma unroll
        for (int ks = 0; ks < 2; ++ks) {
            const int kk2 = ks * 64 + lg * 16;
            short8v a[4], bq[4];
            #pragma unroll
            for (int mt = 0; mt < 4; ++mt)
                a[mt] = *(const short8v*)(As + swz(wm + mt * 16 + l15, kk2));
            #pragma unroll
            for (int nt = 0; nt < 4; ++nt)
                bq[nt] = *(const short8v*)(Bs + swz(wn + nt * 16 + l15, kk2));
            #pragma unroll
            for (int mt = 0; mt < 4; ++mt)
                #pragma unroll
                for (int nt = 0; nt < 4; ++nt)
                    acc[mt][nt] = __builtin_amdgcn_mfma_f32_16x16x32_bf16(
                        a[mt], bq[nt], acc[mt][nt], 0, 0, 0);
        }
    }

    #pragma unroll
    for (int mt = 0; mt < 4; ++mt)
        #pragma unroll
        for (int j = 0; j < 4; ++j) {
            int ch = cb + wm + mt * 16 + lg * 4 + j;
            size_t base = ((size_t)b * CIN + ch) * HW + p0;
            float bias = bb_[ch];
            #pragma unroll
            for (int nt = 0; nt < 4; ++nt) {
                int px = wn + nt * 16 + l15;
                out[base + px] = x[base + px] + acc[mt][nt][j] + bias;
            }
        }
}

extern "C" void kernel_launch(void* const* d_in, const int* in_sizes, int n_in,
                              void* d_out, int out_size, void* d_ws, size_t ws_size,
                              hipStream_t stream)
{
    const float* x  = (const float*)d_in[0];
    const float* wt = (const float*)d_in[1];
    const float* bt = (const float*)d_in[2];
    const float* wp = (const float*)d_in[3];
    const float* bp = (const float*)d_in[4];
    const float* wg = (const float*)d_in[5];
    const float* bg = (const float*)d_in[6];
    const float* wb = (const float*)d_in[7];
    const float* bb = (const float*)d_in[8];
    float* out = (float*)d_out;

    const size_t FEAT = (size_t)NPIX * CO;       // 9.4M elems; bf16 = 18.9MB each
    unsigned short* th = (unsigned short*)d_ws;
    unsigned short* ph = th + FEAT;
    unsigned short* gf = ph + FEAT;
    unsigned short* wa = gf + FEAT;              // 75.5MB total

    hipLaunchKernelGGL(k1_mfma, dim3(1728), dim3(256), 0, stream,
                       x, wt, bt, wp, bp, wg, bg, th, ph, gf);
    hipLaunchKernelGGL(k_attn, dim3(1152), dim3(256), 0, stream,
                       th, ph, gf, wa);
    hipLaunchKernelGGL(k3_mfma, dim3(1152), dim3(256), 0, stream,
                       wa, wb, bb, x, out);
}

// Round 7
// 221.105 us; speedup vs baseline: 1.1941x; 1.1941x over previous
//
#include <hip/hip_runtime.h>
#include <hip/hip_bf16.h>
#include <math.h>

#define HW   9216
#define WIMG 96
#define NPIX 73728  // 8 * 9216
#define CIN  256
#define CO   128

typedef __attribute__((ext_vector_type(8))) short short8v;        // 8 bf16 (4 VGPR)
typedef __attribute__((ext_vector_type(8))) unsigned short u16x8; // 8 bf16 raw
typedef __attribute__((ext_vector_type(4))) float f32x4;          // MFMA acc

__device__ __forceinline__ unsigned short f2bf(float f) {
    __hip_bfloat16 h = __float2bfloat16(f);
    return __builtin_bit_cast(unsigned short, h);
}
__device__ __forceinline__ float bf2f(unsigned short u) {
    unsigned v = ((unsigned)u) << 16;
    return __builtin_bit_cast(float, v);
}

// Row-XOR swizzle for [rows][64k] bf16 tiles (128B rows): reads/writes <=2-way.
__device__ __forceinline__ int swz(int row, int kb) {
    return (row * 128) + (kb ^ ((row & 7) << 4));
}
// Same for 256B rows ([rows][128ch] bf16).
__device__ __forceinline__ int swz2(int row, int kb) {
    return (row * 256) + (kb ^ ((row & 7) << 4));
}

// ---------------------------------------------------------------------------
// K1 (MFMA): feat[px][128] = bf16(x[px][:]).bf16(W^T)+b  — exact R4 revert
// (74us proven). grid 1728 = 576 tiles x 3 maps, XCD swizzle + %3 siblings.
// ---------------------------------------------------------------------------
__global__ __launch_bounds__(256) void k1_mfma(
    const float* __restrict__ x,
    const float* __restrict__ wt, const float* __restrict__ bt,
    const float* __restrict__ wp, const float* __restrict__ bp,
    const float* __restrict__ wg, const float* __restrict__ bg,
    unsigned short* __restrict__ th, unsigned short* __restrict__ ph,
    unsigned short* __restrict__ gf)
{
    __shared__ char As[128 * 128];  // [128 px][64 k] bf16, swizzled (16KB)
    __shared__ char Bs[128 * 128];  // [128 n ][64 k] bf16, swizzled (16KB)

    const int t   = threadIdx.x;
    const int bid = blockIdx.x;
    const int lb  = (bid & 7) * 216 + (bid >> 3);   // 1728 wg, bijective
    const int nb  = lb % 3;                         // siblings adjacent on XCD
    const int bx  = lb / 3;

    const float* W  = (nb == 0) ? wt : (nb == 1) ? wp : wg;
    const float* Bv = (nb == 0) ? bt : (nb == 1) ? bp : bg;
    unsigned short* O = (nb == 0) ? th : (nb == 1) ? ph : gf;

    const int P0 = bx * 128;               // 9216 % 128 == 0: no batch straddle
    const int b  = P0 / HW;
    const int p0 = P0 - b * HW;
    const float* xb = x + (size_t)b * CIN * HW + p0;

    const int wid = t >> 6, lane = t & 63;
    const int wm = (wid & 1) * 64, wn = (wid >> 1) * 64;
    const int l15 = lane & 15, lg = lane >> 4;

    f32x4 acc[4][4] = {};

    for (int kt = 0; kt < CIN; kt += 64) {
        if (kt) __syncthreads();
        // ---- stage A: x[kt+k][P0+pp] -> As[pp][k]  (transpose + cvt) ----
        #pragma unroll
        for (int it = 0; it < 8; ++it) {
            int kq = ((t >> 4) & 3) + (it & 3) * 4;                  // 0..15
            int pp = (t & 15) + ((t >> 6) << 4) + ((it >> 2) << 6);  // 0..127
            ushort4 v;
            v.x = f2bf(xb[(size_t)(kt + kq * 4 + 0) * HW + pp]);
            v.y = f2bf(xb[(size_t)(kt + kq * 4 + 1) * HW + pp]);
            v.z = f2bf(xb[(size_t)(kt + kq * 4 + 2) * HW + pp]);
            v.w = f2bf(xb[(size_t)(kt + kq * 4 + 3) * HW + pp]);
            *(ushort4*)(As + swz(pp, kq * 8)) = v;
        }
        // ---- stage B: W[n][kt+k] -> Bs[n][k] (float4 loads) ----
        #pragma unroll
        for (int it = 0; it < 8; ++it) {
            int kq = t & 15;
            int n  = (t >> 4) + it * 16;
            float4 w4 = *(const float4*)(W + (size_t)n * CIN + kt + kq * 4);
            ushort4 v;
            v.x = f2bf(w4.x); v.y = f2bf(w4.y); v.z = f2bf(w4.z); v.w = f2bf(w4.w);
            *(ushort4*)(Bs + swz(n, kq * 8)) = v;
        }
        __syncthreads();
        #pragma unroll
        for (int ks = 0; ks < 2; ++ks) {
            const int kk2 = ks * 64 + lg * 16;
            short8v a[4], bq[4];
            #pragma unroll
            for (int mt = 0; mt < 4; ++mt)
                a[mt] = *(const short8v*)(As + swz(wm + mt * 16 + l15, kk2));
            #pragma unroll
            for (int nt = 0; nt < 4; ++nt)
                bq[nt] = *(const short8v*)(Bs + swz(wn + nt * 16 + l15, kk2));
            #pragma unroll
            for (int mt = 0; mt < 4; ++mt)
                #pragma unroll
                for (int nt = 0; nt < 4; ++nt)
                    acc[mt][nt] = __builtin_amdgcn_mfma_f32_16x16x32_bf16(
                        a[mt], bq[nt], acc[mt][nt], 0, 0, 0);
        }
    }

    float bias[4];
    #pragma unroll
    for (int nt = 0; nt < 4; ++nt) bias[nt] = Bv[wn + nt * 16 + l15];
    #pragma unroll
    for (int mt = 0; mt < 4; ++mt)
        #pragma unroll
        for (int j = 0; j < 4; ++j) {
            size_t row = (size_t)(P0 + wm + mt * 16 + lg * 4 + j) * CO;
            #pragma unroll
            for (int nt = 0; nt < 4; ++nt)
                O[row + wn + nt * 16 + l15] = f2bf(acc[mt][nt][j] + bias[nt]);
        }
}

// ---------------------------------------------------------------------------
// K23 fused: phase 1 = cosine attention (one quad per pixel, 64 px/block),
// wa written to LDS Was[64 px][128 ch] bf16 (swz2). phase 2 = back-GEMM
// D[ch][px] = w_back . Was^T with fused residual + bias.
// LDS 48KB -> 3 blocks/CU. Grid 1152 (image-per-XCD swizzle). Saves the
// 38MB wa round-trip + K3's B staging + one launch vs separate K2/K3.
// ---------------------------------------------------------------------------
__global__ __launch_bounds__(256) void k23_fused(
    const unsigned short* __restrict__ th, const unsigned short* __restrict__ ph,
    const unsigned short* __restrict__ gf, const float* __restrict__ wb,
    const float* __restrict__ bb_, const float* __restrict__ x,
    float* __restrict__ out)
{
    __shared__ char Was[64 * 256];  // [64 px][128 ch] bf16, swz2 (32KB)
    __shared__ char Ws[128 * 128];  // [128 ch][64 k] bf16, swz (16KB)

    const int t   = threadIdx.x;
    const int bid = blockIdx.x;
    const int lb  = (bid & 7) * 144 + (bid >> 3);   // 1152 wg, bijective
    const int P0  = lb * 64;               // 9216 % 64 == 0: no batch straddle
    const int b   = P0 / HW;
    const int p0  = P0 - b * HW;
    const size_t ib = (size_t)b * HW;

    // ================= phase 1: attention for pixel P0+sq =================
    {
        const int sq = t >> 2, q = t & 3;
        const int P  = P0 + sq;
        const int p  = p0 + sq;
        const int h  = p / WIMG;
        const int w  = p - h * WIMG;

        size_t nbase[9];
        #pragma unroll
        for (int n = 0; n < 9; ++n) {
            int hh = h + n / 3 - 1; hh = hh < 0 ? 0 : (hh > 95 ? 95 : hh);
            int w2 = w + n % 3 - 1; w2 = w2 < 0 ? 0 : (w2 > 95 ? 95 : w2);
            nbase[n] = (ib + (size_t)hh * WIMG + w2) * CO + q * 32;
        }

        const u16x8* tv = (const u16x8*)(th + (size_t)P * CO + q * 32);
        float T32[32];
        #pragma unroll
        for (int j = 0; j < 4; ++j) {
            u16x8 v = tv[j];
            #pragma unroll
            for (int e = 0; e < 8; ++e) T32[j * 8 + e] = bf2f(v[e]);
        }
        float t4[4] = {0.f, 0.f, 0.f, 0.f};
        #pragma unroll
        for (int j = 0; j < 4; ++j)
            #pragma unroll
            for (int e = 0; e < 8; ++e)
                t4[j] = fmaf(T32[j * 8 + e], T32[j * 8 + e], t4[j]);
        float tt = (t4[0] + t4[1]) + (t4[2] + t4[3]);
        tt += __shfl_xor(tt, 1);
        tt += __shfl_xor(tt, 2);
        const float st = sqrtf(tt);

        float score[9];
        #pragma unroll
        for (int n = 0; n < 9; ++n) {
            const u16x8* pv = (const u16x8*)(ph + nbase[n]);
            float d4[4] = {0.f, 0.f, 0.f, 0.f};
            float p4[4] = {0.f, 0.f, 0.f, 0.f};
            #pragma unroll
            for (int j = 0; j < 4; ++j) {
                u16x8 v = pv[j];
                #pragma unroll
                for (int e = 0; e < 8; ++e) {
                    float f = bf2f(v[e]);
                    d4[j] = fmaf(T32[j * 8 + e], f, d4[j]);
                    p4[j] = fmaf(f, f, p4[j]);
                }
            }
            float d  = (d4[0] + d4[1]) + (d4[2] + d4[3]);
            float pp = (p4[0] + p4[1]) + (p4[2] + p4[3]);
            d  += __shfl_xor(d, 1);  d  += __shfl_xor(d, 2);
            pp += __shfl_xor(pp, 1); pp += __shfl_xor(pp, 2);
            float den = fmaxf(sqrtf(pp) * st, 1e-8f);
            score[n] = d / den;
        }

        float mx = score[0];
        #pragma unroll
        for (int n = 1; n < 9; ++n) mx = fmaxf(mx, score[n]);
        float sum = 0.f;
        #pragma unroll
        for (int n = 0; n < 9; ++n) { score[n] = __expf(score[n] - mx); sum += score[n]; }
        const float inv = 1.f / sum;

        float acc1[32];
        #pragma unroll
        for (int k = 0; k < 32; ++k) acc1[k] = 0.f;

        #pragma unroll
        for (int n = 0; n < 9; ++n) {
            const u16x8* gv = (const u16x8*)(gf + nbase[n]);
            float a = score[n] * inv;
            #pragma unroll
            for (int j = 0; j < 4; ++j) {
                u16x8 v = gv[j];
                #pragma unroll
                for (int e = 0; e < 8; ++e)
                    acc1[j * 8 + e] = fmaf(a, bf2f(v[e]), acc1[j * 8 + e]);
            }
        }

        // wa row sq, ch q*32..q*32+31 -> LDS (4 x 16B, swizzled)
        #pragma unroll
        for (int j = 0; j < 4; ++j) {
            u16x8 o;
            #pragma unroll
            for (int e = 0; e < 8; ++e) o[e] = f2bf(acc1[j * 8 + e]);
            *(u16x8*)(Was + swz2(sq, q * 64 + j * 16)) = o;
        }
    }
    __syncthreads();

    // ================= phase 2: out = x + w_back . wa^T + b ================
    const int wid = t >> 6, lane = t & 63;
    const int wm = (wid & 1) * 64;          // ch within 128-half
    const int wn = (wid >> 1) * 32;         // px within 64
    const int l15 = lane & 15, lg = lane >> 4;

    for (int cb = 0; cb < CIN; cb += 128) {
        f32x4 acc[4][2] = {};
        for (int kt = 0; kt < CO; kt += 64) {
            __syncthreads();               // protect Ws overwrite
            #pragma unroll
            for (int it = 0; it < 8; ++it) {
                int kq = t & 15;
                int n  = (t >> 4) + it * 16;
                float4 w4 = *(const float4*)(wb + (size_t)(cb + n) * CO + kt + kq * 4);
                ushort4 v;
                v.x = f2bf(w4.x); v.y = f2bf(w4.y); v.z = f2bf(w4.z); v.w = f2bf(w4.w);
                *(ushort4*)(Ws + swz(n, kq * 8)) = v;
            }
            __syncthreads();
            #pragma unroll
            for (int ks = 0; ks < 2; ++ks) {
                const int kk2 = ks * 64 + lg * 16;
                short8v a[4], bq[2];
                #pragma unroll
                for (int mt = 0; mt < 4; ++mt)
                    a[mt] = *(const short8v*)(Ws + swz(wm + mt * 16 + l15, kk2));
                #pragma unroll
                for (int nt = 0; nt < 2; ++nt)
                    bq[nt] = *(const short8v*)(Was + swz2(wn + nt * 16 + l15, kt * 2 + kk2));
                #pragma unroll
                for (int mt = 0; mt < 4; ++mt)
                    #pragma unroll
                    for (int nt = 0; nt < 2; ++nt)
                        acc[mt][nt] = __builtin_amdgcn_mfma_f32_16x16x32_bf16(
                            a[mt], bq[nt], acc[mt][nt], 0, 0, 0);
            }
        }
        // epilogue: D[ch][px]; residual + bias; coalesced along px
        #pragma unroll
        for (int mt = 0; mt < 4; ++mt)
            #pragma unroll
            for (int j = 0; j < 4; ++j) {
                int ch = cb + wm + mt * 16 + lg * 4 + j;
                size_t base = ((size_t)b * CIN + ch) * HW + p0;
                float bias = bb_[ch];
                #pragma unroll
                for (int nt = 0; nt < 2; ++nt) {
                    int px = wn + nt * 16 + l15;
                    out[base + px] = x[base + px] + acc[mt][nt][j] + bias;
                }
            }
    }
}

extern "C" void kernel_launch(void* const* d_in, const int* in_sizes, int n_in,
                              void* d_out, int out_size, void* d_ws, size_t ws_size,
                              hipStream_t stream)
{
    const float* x  = (const float*)d_in[0];
    const float* wt = (const float*)d_in[1];
    const float* bt = (const float*)d_in[2];
    const float* wp = (const float*)d_in[3];
    const float* bp = (const float*)d_in[4];
    const float* wg = (const float*)d_in[5];
    const float* bg = (const float*)d_in[6];
    const float* wb = (const float*)d_in[7];
    const float* bb = (const float*)d_in[8];
    float* out = (float*)d_out;

    const size_t FEAT = (size_t)NPIX * CO;       // 9.4M elems; bf16 = 18.9MB each
    unsigned short* th = (unsigned short*)d_ws;
    unsigned short* ph = th + FEAT;
    unsigned short* gf = ph + FEAT;              // 56.6MB total

    hipLaunchKernelGGL(k1_mfma, dim3(1728), dim3(256), 0, stream,
                       x, wt, bt, wp, bp, wg, bg, th, ph, gf);
    hipLaunchKernelGGL(k23_fused, dim3(1152), dim3(256), 0, stream,
                       th, ph, gf, wb, bb, x, out);
}